// Round 5
// baseline (121.543 us; speedup 1.0000x reference)
//
#include <hip/hip_runtime.h>

#define S_LEN 2048
#define HID   1024
#define NHEAD 16
#define NKVH  4
#define HDIM  64
#define NPROJ 1536   // projection output cols: 1024 Q + 256 K + 256 V
#define QKSTR 1280   // qkv buffer row stride: Q(1024) + K(256); V goes to vT transposed

typedef __bf16 bf16x8 __attribute__((ext_vector_type(8)));
typedef __bf16 bf16x4 __attribute__((ext_vector_type(4)));
typedef __bf16 bf16x2 __attribute__((ext_vector_type(2)));
typedef float  f32x4  __attribute__((ext_vector_type(4)));
typedef unsigned u32x4 __attribute__((ext_vector_type(4)));

typedef const __attribute__((address_space(1))) void* gas_ptr;
typedef __attribute__((address_space(3))) void*       las_ptr;

// scale = (1/sqrt(1024)) * log2(e): fold softmax scale + base-2 conversion into Q
#define QSCALE 0.04508422f

__device__ __forceinline__ unsigned short f2bf(float f) {
    unsigned u = __builtin_bit_cast(unsigned, f);
    u = u + 0x7FFFu + ((u >> 16) & 1u);   // round-to-nearest-even
    return (unsigned short)(u >> 16);
}

// ---------------- fp32 -> bf16 conversion of x and all weights ----------------
__global__ __launch_bounds__(256) void cvt_all(
    const float* __restrict__ x,  const float* __restrict__ wq,
    const float* __restrict__ wk, const float* __restrict__ wv,
    unsigned short* __restrict__ xbf, unsigned short* __restrict__ wbf)
{
    const long nx  = (long)S_LEN * HID;     // 2097152
    const long nwq = (long)HID * HID;       // 1048576
    const long nwk = (long)256 * HID;       // 262144
    long i = (long)(blockIdx.x * 256 + threadIdx.x) * 4;
    const float* src; unsigned short* dst;
    if (i < nx)                  { src = x  + i;                 dst = xbf + i; }
    else if (i < nx + nwq)       { long j = i - nx;              src = wq + j; dst = wbf + j; }
    else if (i < nx + nwq + nwk) { long j = i - nx - nwq;        src = wk + j; dst = wbf + nwq + j; }
    else                         { long j = i - nx - nwq - nwk;  src = wv + j; dst = wbf + nwq + nwk + j; }
    float4 v = *(const float4*)src;
    ushort4 o; o.x = f2bf(v.x); o.y = f2bf(v.y); o.z = f2bf(v.z); o.w = f2bf(v.w);
    *(ushort4*)dst = o;
}

// ---------------- QKV projection (unchanged from passing R2) ----------------
__global__ __launch_bounds__(256, 2) void proj_gemm(
    const unsigned short* __restrict__ xbf,
    const unsigned short* __restrict__ wbf,
    unsigned short* __restrict__ qkv,
    unsigned short* __restrict__ vT)
{
    __shared__ unsigned short At[2][64 * 64];
    __shared__ unsigned short Bt[2][96 * 64];
    const int tid = threadIdx.x;
    const int w = tid >> 6, l = tid & 63;
    const int quad = l >> 4, lane16 = l & 15;
    const int m0 = blockIdx.y * 64, n0 = blockIdx.x * 96;
    const int wm = (w & 1) * 32, wn = (w >> 1) * 48;

    const int srow = l >> 3;
    const int scol = ((l & 7) ^ srow) * 8;

    f32x4 acc[2][3] = {};

    #define STAGE(KT, BUF)                                                              \
        do {                                                                            \
            _Pragma("unroll")                                                           \
            for (int c = 0; c < 2; ++c) {                                               \
                const int rbase = w * 16 + c * 8;                                       \
                const unsigned short* ga =                                              \
                    xbf + (long)(m0 + rbase + srow) * HID + (KT) + scol;                \
                __builtin_amdgcn_global_load_lds((gas_ptr)ga,                           \
                    (las_ptr)&At[BUF][rbase * 64], 16, 0, 0);                           \
            }                                                                           \
            _Pragma("unroll")                                                           \
            for (int c = 0; c < 3; ++c) {                                               \
                const int rbase = w * 24 + c * 8;                                       \
                const unsigned short* gb =                                              \
                    wbf + (long)(n0 + rbase + srow) * HID + (KT) + scol;                \
                __builtin_amdgcn_global_load_lds((gas_ptr)gb,                           \
                    (las_ptr)&Bt[BUF][rbase * 64], 16, 0, 0);                           \
            }                                                                           \
        } while (0)

    STAGE(0, 0);

    for (int i = 0; i < 16; ++i) {
        const int cur = i & 1;
        __syncthreads();
        if (i + 1 < 16) STAGE((i + 1) * 64, cur ^ 1);

        #pragma unroll
        for (int ks = 0; ks < 2; ++ks) {
            const int swz = ((ks * 4 + quad) ^ (lane16 & 7)) * 8;
            bf16x8 a[2], b[3];
            #pragma unroll
            for (int mi = 0; mi < 2; ++mi)
                a[mi] = *(const bf16x8*)&At[cur][(wm + mi * 16 + lane16) * 64 + swz];
            #pragma unroll
            for (int ni = 0; ni < 3; ++ni)
                b[ni] = *(const bf16x8*)&Bt[cur][(wn + ni * 16 + lane16) * 64 + swz];
            #pragma unroll
            for (int mi = 0; mi < 2; ++mi)
                #pragma unroll
                for (int ni = 0; ni < 3; ++ni)
                    acc[mi][ni] = __builtin_amdgcn_mfma_f32_16x16x32_bf16(a[mi], b[ni], acc[mi][ni], 0, 0, 0);
        }
    }
    #undef STAGE

    #pragma unroll
    for (int mi = 0; mi < 2; ++mi) {
        const int row = m0 + wm + mi * 16 + quad * 4;
        #pragma unroll
        for (int ni = 0; ni < 3; ++ni) {
            const int col = n0 + wn + ni * 16 + lane16;
            #pragma unroll
            for (int r = 0; r < 4; ++r) {
                const float v = acc[mi][ni][r];
                if (col < 1024)
                    qkv[(long)(row + r) * QKSTR + col] = f2bf(v * QSCALE);
                else if (col < 1280)
                    qkv[(long)(row + r) * QKSTR + col] = f2bf(v);
                else
                    vT[(long)(col - 1280) * S_LEN + (row + r)] = f2bf(v);
            }
        }
    }
}

// ---------------- flash attention (MFMA), causal, GQA rep=4 ----------------
// R5: 2-wave blocks (128 thr), 32 q-rows per wave (two 16-row subtiles).
// Rationale (R4 post-mortem): attn is DS-pipe/barrier-amortization bound.
// K/V fragment ds_reads are loaded ONCE per wave and reused for BOTH
// q-subtiles -> frag-read volume per 64 q-rows halves (was: 4 waves each
// re-reading the tile for only 16 rows); per-barrier useful work doubles.
// Everything else is the R2/R4-proven structure: coalesced reg-prefetch
// staging, double-buffered K/V, ONE barrier per iteration (stores(kt+2) to
// buf[cur] are separated from PV reads(kt) of buf[cur] by barrier(kt+1),
// which a wave passes only after its PV MFMAs consumed the reads), in-reg
// butterfly P-redistribution (no P LDS), setprio around MFMA clusters.
#define KSTR 72   // LDS row stride (ushorts): multiple of 8 -> 16B-aligned b128
__global__ __launch_bounds__(128, 2) void attn(
    const unsigned short* __restrict__ qkv,
    const unsigned short* __restrict__ vT,
    float* __restrict__ out)
{
    __shared__ unsigned short Kt[2][64 * KSTR];     // K tile  [kv][d]
    __shared__ unsigned short Vt[2][64 * KSTR];     // V^T tile [d][kv]

    const int tid = threadIdx.x;
    const int w = tid >> 6, l = tid & 63;           // w in {0,1}
    const int quad = l >> 4, lane16 = l & 15;
    const int bx = blockIdx.x, by = blockIdx.y;
    const int qt = (by & 8) ? (31 - bx) : bx;       // balanced pairing remap
    const int h  = by;
    const int kh = h >> 2;
    const int qcol = h * 64;
    const int kcol = 1024 + kh * 64;

    // Q fragments for the wave's two subtiles m=0,1:
    // qrow_m = qt*64 + w*32 + m*16 + lane16  (B-layout: n=lane16, k=quad*8+j)
    bf16x8 qa[2][2];
    #pragma unroll
    for (int m = 0; m < 2; ++m) {
        const long qrow = (long)(qt * 64 + w * 32 + m * 16 + lane16);
        qa[m][0] = *(const bf16x8*)&qkv[qrow * QKSTR + qcol + quad * 8];
        qa[m][1] = *(const bf16x8*)&qkv[qrow * QKSTR + qcol + 32 + quad * 8];
    }

    f32x4 o[2][4] = {};
    float rsum[2][4] = {};

    // staging coords: 128 thr x 32 ushorts (64B) cover each 64x64 tile
    const int sr = tid >> 1, ss = tid & 1;          // row 0..63, 32-ushort half
    const long vrow = (long)(kh * 64 + sr) * S_LEN;

    // butterfly source lanes (constant): srcA = L + 32*(Q&1), srcB = srcA+16
    const int srcA = lane16 + ((l & 16) << 1);
    const int srcB = srcA + 16;
    const bool up = (l >= 32);                      // Q>>1

    // prologue: prefetch tile 0 into registers (4 K + 4 V bf16x8 per thread)
    bf16x8 kr[4], vr[4];
    {
        const long gk = (long)sr * QKSTR + kcol + ss * 32;
        const long gv = vrow + ss * 32;
        #pragma unroll
        for (int j = 0; j < 4; ++j) {
            kr[j] = *(const bf16x8*)&qkv[gk + j * 8];
            vr[j] = *(const bf16x8*)&vT[gv + j * 8];
        }
    }

    for (int kt = 0; kt <= qt; ++kt) {
        const int cur = kt & 1;
        // (A) store prefetched tile into buf[cur]; prefetch next into regs
        #pragma unroll
        for (int j = 0; j < 4; ++j) {
            *(bf16x8*)&Kt[cur][sr * KSTR + ss * 32 + j * 8] = kr[j];
            *(bf16x8*)&Vt[cur][sr * KSTR + ss * 32 + j * 8] = vr[j];
        }
        if (kt < qt) {                        // uniform branch
            const long gk = (long)((kt + 1) * 64 + sr) * QKSTR + kcol + ss * 32;
            const long gv = vrow + (kt + 1) * 64 + ss * 32;
            #pragma unroll
            for (int j = 0; j < 4; ++j) {
                kr[j] = *(const bf16x8*)&qkv[gk + j * 8];
                vr[j] = *(const bf16x8*)&vT[gv + j * 8];
            }
        }
        __syncthreads();                      // (B) staging[cur] visible

        // K fragments read ONCE, reused for both q-subtiles
        bf16x8 kb[8];
        #pragma unroll
        for (int t = 0; t < 4; ++t) {
            kb[2 * t]     = *(const bf16x8*)&Kt[cur][(t * 16 + lane16) * KSTR + quad * 8];
            kb[2 * t + 1] = *(const bf16x8*)&Kt[cur][(t * 16 + lane16) * KSTR + 32 + quad * 8];
        }

        // S^T = K Q^T per subtile; C layout: row=kv=t*16+quad*4+r, col=lane16
        f32x4 sacc[2][4] = {};
        __builtin_amdgcn_s_setprio(1);
        #pragma unroll
        for (int m = 0; m < 2; ++m)
            #pragma unroll
            for (int t = 0; t < 4; ++t) {
                sacc[m][t] = __builtin_amdgcn_mfma_f32_16x16x32_bf16(kb[2 * t],     qa[m][0], sacc[m][t], 0, 0, 0);
                sacc[m][t] = __builtin_amdgcn_mfma_f32_16x16x32_bf16(kb[2 * t + 1], qa[m][1], sacc[m][t], 0, 0, 0);
            }
        __builtin_amdgcn_s_setprio(0);

        // causal mask on diagonal tile: kv > qrow (block-local indices)
        if (kt == qt) {
            #pragma unroll
            for (int m = 0; m < 2; ++m) {
                const int qloc = w * 32 + m * 16 + lane16;
                #pragma unroll
                for (int t = 0; t < 4; ++t) {
                    const int kvw = t * 16 + quad * 4;
                    #pragma unroll
                    for (int r = 0; r < 4; ++r)
                        if (kvw + r > qloc) sacc[m][t][r] = -3.0e38f;
                }
            }
        }

        // softmax + pack + butterfly per subtile -> PV A-fragments
        bf16x8 pa[2][2];
        #pragma unroll
        for (int m = 0; m < 2; ++m) {
            unsigned h8[8];
            #pragma unroll
            for (int t = 0; t < 4; ++t) {
                const float p0 = __builtin_amdgcn_exp2f(sacc[m][t][0]);
                const float p1 = __builtin_amdgcn_exp2f(sacc[m][t][1]);
                const float p2 = __builtin_amdgcn_exp2f(sacc[m][t][2]);
                const float p3 = __builtin_amdgcn_exp2f(sacc[m][t][3]);
                rsum[m][t] += (p0 + p1) + (p2 + p3);
                bf16x2 lo, hi;
                lo[0] = (__bf16)p0; lo[1] = (__bf16)p1;
                hi[0] = (__bf16)p2; hi[1] = (__bf16)p3;
                h8[t * 2]     = __builtin_bit_cast(unsigned, lo);
                h8[t * 2 + 1] = __builtin_bit_cast(unsigned, hi);
            }
            unsigned sA[8], sB[8];
            #pragma unroll
            for (int i = 0; i < 8; ++i) {
                sA[i] = __shfl(h8[i], srcA);
                sB[i] = __shfl(h8[i], srcB);
            }
            u32x4 w0, w1;
            w0[0] = up ? sA[2] : sA[0];  w0[1] = up ? sA[3] : sA[1];
            w0[2] = up ? sB[2] : sB[0];  w0[3] = up ? sB[3] : sB[1];
            w1[0] = up ? sA[6] : sA[4];  w1[1] = up ? sA[7] : sA[5];
            w1[2] = up ? sB[6] : sB[4];  w1[3] = up ? sB[7] : sB[5];
            pa[m][0] = __builtin_bit_cast(bf16x8, w0);
            pa[m][1] = __builtin_bit_cast(bf16x8, w1);
        }

        // V fragments read ONCE, reused for both q-subtiles
        // O += P V  (A = P [m=qrow][k=kv], B = V^T [n=d][k=kv])
        __builtin_amdgcn_s_setprio(1);
        #pragma unroll
        for (int t = 0; t < 4; ++t) {
            bf16x8 vb0 = *(const bf16x8*)&Vt[cur][(t * 16 + lane16) * KSTR + quad * 8];
            o[0][t] = __builtin_amdgcn_mfma_f32_16x16x32_bf16(pa[0][0], vb0, o[0][t], 0, 0, 0);
            o[1][t] = __builtin_amdgcn_mfma_f32_16x16x32_bf16(pa[1][0], vb0, o[1][t], 0, 0, 0);
        }
        #pragma unroll
        for (int t = 0; t < 4; ++t) {
            bf16x8 vb1 = *(const bf16x8*)&Vt[cur][(t * 16 + lane16) * KSTR + 32 + quad * 8];
            o[0][t] = __builtin_amdgcn_mfma_f32_16x16x32_bf16(pa[0][1], vb1, o[0][t], 0, 0, 0);
            o[1][t] = __builtin_amdgcn_mfma_f32_16x16x32_bf16(pa[1][1], vb1, o[1][t], 0, 0, 0);
        }
        __builtin_amdgcn_s_setprio(0);
    }

    // per-subtile row-sum reduce + normalize + store
    #pragma unroll
    for (int m = 0; m < 2; ++m) {
        float total = (rsum[m][0] + rsum[m][1]) + (rsum[m][2] + rsum[m][3]);
        total += __shfl_xor(total, 16);
        total += __shfl_xor(total, 32);
        const float invt = 1.0f / total;
        float inv[4];
        #pragma unroll
        for (int r = 0; r < 4; ++r)
            inv[r] = __shfl(invt, quad * 4 + r);

        const int orow = qt * 64 + w * 32 + m * 16 + quad * 4;
        #pragma unroll
        for (int t = 0; t < 4; ++t) {
            const int col = h * 64 + t * 16 + lane16;
            #pragma unroll
            for (int r = 0; r < 4; ++r)
                out[(long)(orow + r) * (NHEAD * HDIM) + col] = o[m][t][r] * inv[r];
        }
    }
}

extern "C" void kernel_launch(void* const* d_in, const int* in_sizes, int n_in,
                              void* d_out, int out_size, void* d_ws, size_t ws_size,
                              hipStream_t stream) {
    const float* x  = (const float*)d_in[0];
    const float* wq = (const float*)d_in[1];
    const float* wk = (const float*)d_in[2];
    const float* wv = (const float*)d_in[3];
    float* out = (float*)d_out;

    unsigned short* xbf = (unsigned short*)d_ws;                 // 2048*1024
    unsigned short* wbf = xbf + (size_t)S_LEN * HID;             // 1536*1024
    unsigned short* qkv = wbf + (size_t)NPROJ * HID;             // 2048*1280 (Q+K)
    unsigned short* vT  = qkv + (size_t)S_LEN * QKSTR;           // 256*2048  (V^T)

    cvt_all<<<dim3(3584), dim3(256), 0, stream>>>(x, wq, wk, wv, xbf, wbf);
    proj_gemm<<<dim3(16, 32), dim3(256), 0, stream>>>(xbf, wbf, qkv, vT);
    attn<<<dim3(32, 16), dim3(128), 0, stream>>>(qkv, vT, out);
}

// Round 6
// 115.767 us; speedup vs baseline: 1.0499x; 1.0499x over previous
//
#include <hip/hip_runtime.h>

#define S_LEN 2048
#define HID   1024
#define NHEAD 16
#define NKVH  4
#define HDIM  64
#define NPROJ 1536   // projection output cols: 1024 Q + 256 K + 256 V
#define QKSTR 1280   // qkv buffer row stride: Q(1024) + K(256); V goes to vT transposed

typedef __bf16 bf16x8 __attribute__((ext_vector_type(8)));
typedef __bf16 bf16x4 __attribute__((ext_vector_type(4)));
typedef float  f32x4  __attribute__((ext_vector_type(4)));
typedef short  s16x4  __attribute__((ext_vector_type(4)));

typedef const __attribute__((address_space(1))) void* gas_ptr;
typedef __attribute__((address_space(3))) void*       las_ptr;

// scale = (1/sqrt(1024)) * log2(e): fold softmax scale + base-2 conversion into Q
#define QSCALE 0.04508422f

__device__ __forceinline__ unsigned short f2bf(float f) {
    unsigned u = __builtin_bit_cast(unsigned, f);
    u = u + 0x7FFFu + ((u >> 16) & 1u);   // round-to-nearest-even
    return (unsigned short)(u >> 16);
}

// 16x16x16 bf16 MFMA (K=16): B-layout k = quad*4+j matches the S^T output
// granularity (row = quad*4+r) exactly -> softmax feeds PV with ZERO
// cross-lane movement. gfx90a-lineage builtin; gfx950 carries the instr
// (cdna4_isa §10: v_mfma_f32_16x16x16_bf16, A 2 regs, B 2 regs, C 4).
__device__ __forceinline__ f32x4 mfma_16x16x16_bf16(s16x4 a, s16x4 b, f32x4 c) {
#if __has_builtin(__builtin_amdgcn_mfma_f32_16x16x16bf16_1k)
    return __builtin_amdgcn_mfma_f32_16x16x16bf16_1k(a, b, c, 0, 0, 0);
#else
    f32x4 d = c;
    asm volatile("s_nop 1\n\tv_mfma_f32_16x16x16_bf16 %0, %1, %2, %0\n\ts_nop 3"
                 : "+v"(d) : "v"(a), "v"(b));
    return d;
#endif
}

// ---------------- fp32 -> bf16 conversion of x and all weights ----------------
__global__ __launch_bounds__(256) void cvt_all(
    const float* __restrict__ x,  const float* __restrict__ wq,
    const float* __restrict__ wk, const float* __restrict__ wv,
    unsigned short* __restrict__ xbf, unsigned short* __restrict__ wbf)
{
    const long nx  = (long)S_LEN * HID;     // 2097152
    const long nwq = (long)HID * HID;       // 1048576
    const long nwk = (long)256 * HID;       // 262144
    long i = (long)(blockIdx.x * 256 + threadIdx.x) * 4;
    const float* src; unsigned short* dst;
    if (i < nx)                  { src = x  + i;                 dst = xbf + i; }
    else if (i < nx + nwq)       { long j = i - nx;              src = wq + j; dst = wbf + j; }
    else if (i < nx + nwq + nwk) { long j = i - nx - nwq;        src = wk + j; dst = wbf + nwq + j; }
    else                         { long j = i - nx - nwq - nwk;  src = wv + j; dst = wbf + nwq + nwk + j; }
    float4 v = *(const float4*)src;
    ushort4 o; o.x = f2bf(v.x); o.y = f2bf(v.y); o.z = f2bf(v.z); o.w = f2bf(v.w);
    *(ushort4*)dst = o;
}

// ---------------- QKV projection (unchanged from passing R2) ----------------
__global__ __launch_bounds__(256, 2) void proj_gemm(
    const unsigned short* __restrict__ xbf,
    const unsigned short* __restrict__ wbf,
    unsigned short* __restrict__ qkv,
    unsigned short* __restrict__ vT)
{
    __shared__ unsigned short At[2][64 * 64];
    __shared__ unsigned short Bt[2][96 * 64];
    const int tid = threadIdx.x;
    const int w = tid >> 6, l = tid & 63;
    const int quad = l >> 4, lane16 = l & 15;
    const int m0 = blockIdx.y * 64, n0 = blockIdx.x * 96;
    const int wm = (w & 1) * 32, wn = (w >> 1) * 48;

    const int srow = l >> 3;
    const int scol = ((l & 7) ^ srow) * 8;

    f32x4 acc[2][3] = {};

    #define STAGE(KT, BUF)                                                              \
        do {                                                                            \
            _Pragma("unroll")                                                           \
            for (int c = 0; c < 2; ++c) {                                               \
                const int rbase = w * 16 + c * 8;                                       \
                const unsigned short* ga =                                              \
                    xbf + (long)(m0 + rbase + srow) * HID + (KT) + scol;                \
                __builtin_amdgcn_global_load_lds((gas_ptr)ga,                           \
                    (las_ptr)&At[BUF][rbase * 64], 16, 0, 0);                           \
            }                                                                           \
            _Pragma("unroll")                                                           \
            for (int c = 0; c < 3; ++c) {                                               \
                const int rbase = w * 24 + c * 8;                                       \
                const unsigned short* gb =                                              \
                    wbf + (long)(n0 + rbase + srow) * HID + (KT) + scol;                \
                __builtin_amdgcn_global_load_lds((gas_ptr)gb,                           \
                    (las_ptr)&Bt[BUF][rbase * 64], 16, 0, 0);                           \
            }                                                                           \
        } while (0)

    STAGE(0, 0);

    for (int i = 0; i < 16; ++i) {
        const int cur = i & 1;
        __syncthreads();
        if (i + 1 < 16) STAGE((i + 1) * 64, cur ^ 1);

        #pragma unroll
        for (int ks = 0; ks < 2; ++ks) {
            const int swz = ((ks * 4 + quad) ^ (lane16 & 7)) * 8;
            bf16x8 a[2], b[3];
            #pragma unroll
            for (int mi = 0; mi < 2; ++mi)
                a[mi] = *(const bf16x8*)&At[cur][(wm + mi * 16 + lane16) * 64 + swz];
            #pragma unroll
            for (int ni = 0; ni < 3; ++ni)
                b[ni] = *(const bf16x8*)&Bt[cur][(wn + ni * 16 + lane16) * 64 + swz];
            #pragma unroll
            for (int mi = 0; mi < 2; ++mi)
                #pragma unroll
                for (int ni = 0; ni < 3; ++ni)
                    acc[mi][ni] = __builtin_amdgcn_mfma_f32_16x16x32_bf16(a[mi], b[ni], acc[mi][ni], 0, 0, 0);
        }
    }
    #undef STAGE

    #pragma unroll
    for (int mi = 0; mi < 2; ++mi) {
        const int row = m0 + wm + mi * 16 + quad * 4;
        #pragma unroll
        for (int ni = 0; ni < 3; ++ni) {
            const int col = n0 + wn + ni * 16 + lane16;
            #pragma unroll
            for (int r = 0; r < 4; ++r) {
                const float v = acc[mi][ni][r];
                if (col < 1024)
                    qkv[(long)(row + r) * QKSTR + col] = f2bf(v * QSCALE);
                else if (col < 1280)
                    qkv[(long)(row + r) * QKSTR + col] = f2bf(v);
                else
                    vT[(long)(col - 1280) * S_LEN + (row + r)] = f2bf(v);
            }
        }
    }
}

// ---------------- flash attention (MFMA), causal, GQA rep=4 ----------------
// R6: R2-exact geometry (4 waves x 16 q-rows, 256 thr, double-buffered K/V,
// one barrier/iter, coalesced reg-prefetch staging) with the P-redistribution
// ELIMINATED: PV is computed transposed (O^T = V^T P^T) using 16x16x16 MFMA,
// whose B-operand k-granularity (quad*4+j) equals the S^T output granularity
// (quad*4+r). B-frag = exp2(sacc[t][0..3]) packed in-lane -> softmax feeds
// PV directly in registers. No Pb LDS (36KB total), no bpermute, no fence.
// A-frag = V^T 4 contiguous bf16 (ds_read_b64 from the unchanged Vt layout).
// O^T C-layout: col = q = lane16, row = d_local = quad*4+r -> 1/rowsum is
// lane-local at the epilogue (no broadcast shuffles).
#define KSTR 72   // LDS row stride (ushorts): multiple of 8 -> 16B-aligned b128
__global__ __launch_bounds__(256, 2) void attn(
    const unsigned short* __restrict__ qkv,
    const unsigned short* __restrict__ vT,
    float* __restrict__ out)
{
    __shared__ unsigned short Kt[2][64 * KSTR];     // K tile  [kv][d]
    __shared__ unsigned short Vt[2][64 * KSTR];     // V^T tile [d][kv]

    const int tid = threadIdx.x;
    const int w = tid >> 6, l = tid & 63;
    const int quad = l >> 4, lane16 = l & 15;
    const int bx = blockIdx.x, by = blockIdx.y;
    const int qt = (by & 8) ? (31 - bx) : bx;       // balanced pairing remap
    const int h  = by;
    const int kh = h >> 2;
    const int qcol = h * 64;
    const int kcol = 1024 + kh * 64;

    // Q fragments (B-layout: n=lane16, k=quad*8+j), Q pre-scaled by proj_gemm
    const long qrow = (long)(qt * 64 + w * 16 + lane16);
    bf16x8 qa0 = *(const bf16x8*)&qkv[qrow * QKSTR + qcol + quad * 8];
    bf16x8 qa1 = *(const bf16x8*)&qkv[qrow * QKSTR + qcol + 32 + quad * 8];

    f32x4 oT[4] = {};                // O^T: oT[dt][r] = O[q=lane16][d=dt*16+quad*4+r]
    float rsum[4] = {0.f, 0.f, 0.f, 0.f};

    // staging coords: 256 thr x 16 ushorts cover each 64x64 tile
    const int sr = tid >> 2, ss = tid & 3;
    const long vrow = (long)(kh * 64 + sr) * S_LEN;

    // prologue: prefetch tile 0 into registers
    bf16x8 kr0, kr1, vr0, vr1;
    {
        const long gk = (long)sr * QKSTR + kcol + ss * 16;
        kr0 = *(const bf16x8*)&qkv[gk];
        kr1 = *(const bf16x8*)&qkv[gk + 8];
        const long gv = vrow + ss * 16;
        vr0 = *(const bf16x8*)&vT[gv];
        vr1 = *(const bf16x8*)&vT[gv + 8];
    }

    for (int kt = 0; kt <= qt; ++kt) {
        const int cur = kt & 1;
        // (A) store prefetched tile into buf[cur]; prefetch next into regs
        *(bf16x8*)&Kt[cur][sr * KSTR + ss * 16]     = kr0;
        *(bf16x8*)&Kt[cur][sr * KSTR + ss * 16 + 8] = kr1;
        *(bf16x8*)&Vt[cur][sr * KSTR + ss * 16]     = vr0;
        *(bf16x8*)&Vt[cur][sr * KSTR + ss * 16 + 8] = vr1;
        if (kt < qt) {                        // uniform branch
            const long gk = (long)((kt + 1) * 64 + sr) * QKSTR + kcol + ss * 16;
            kr0 = *(const bf16x8*)&qkv[gk];
            kr1 = *(const bf16x8*)&qkv[gk + 8];
            const long gv = vrow + (kt + 1) * 64 + ss * 16;
            vr0 = *(const bf16x8*)&vT[gv];
            vr1 = *(const bf16x8*)&vT[gv + 8];
        }
        __syncthreads();                      // (B) staging[cur] visible

        // S^T = K Q^T  (64 kv x 16 q-rows); A = K (m=kv), B = Q (n=qrow)
        // C layout per tile t: row = kv = t*16 + quad*4 + r, col = qrow = lane16
        f32x4 sacc[4] = {};
        __builtin_amdgcn_s_setprio(1);
        #pragma unroll
        for (int t = 0; t < 4; ++t) {
            bf16x8 kb0 = *(const bf16x8*)&Kt[cur][(t * 16 + lane16) * KSTR + quad * 8];
            bf16x8 kb1 = *(const bf16x8*)&Kt[cur][(t * 16 + lane16) * KSTR + 32 + quad * 8];
            sacc[t] = __builtin_amdgcn_mfma_f32_16x16x32_bf16(kb0, qa0, sacc[t], 0, 0, 0);
            sacc[t] = __builtin_amdgcn_mfma_f32_16x16x32_bf16(kb1, qa1, sacc[t], 0, 0, 0);
        }
        __builtin_amdgcn_s_setprio(0);

        // causal mask on diagonal tile: kv > qrow  (both local to this 64-block)
        if (kt == qt) {
            #pragma unroll
            for (int t = 0; t < 4; ++t) {
                const int kvw = t * 16 + quad * 4;
                #pragma unroll
                for (int r = 0; r < 4; ++r)
                    if (kvw + r > w * 16 + lane16) sacc[t][r] = -3.0e38f;
            }
        }

        // softmax: p = exp2(s) (bounded; masked -> +0). Lane's 4 values per t
        // ARE the 16x16x16 B-fragment for kv-chunk t: pack in-lane, done.
        s16x4 pfrag[4];
        #pragma unroll
        for (int t = 0; t < 4; ++t) {
            const float p0 = __builtin_amdgcn_exp2f(sacc[t][0]);
            const float p1 = __builtin_amdgcn_exp2f(sacc[t][1]);
            const float p2 = __builtin_amdgcn_exp2f(sacc[t][2]);
            const float p3 = __builtin_amdgcn_exp2f(sacc[t][3]);
            rsum[t] += (p0 + p1) + (p2 + p3);
            bf16x4 pk;
            pk[0] = (__bf16)p0; pk[1] = (__bf16)p1;
            pk[2] = (__bf16)p2; pk[3] = (__bf16)p3;
            pfrag[t] = __builtin_bit_cast(s16x4, pk);
        }

        // O^T += V^T P^T  (16x16x16: A = V^T [m=d_local][k=kv_local],
        // B = P^T [k=kv_local][n=q]); A-frag = 4 contiguous bf16 (b64 read)
        __builtin_amdgcn_s_setprio(1);
        #pragma unroll
        for (int dt = 0; dt < 4; ++dt)
            #pragma unroll
            for (int t = 0; t < 4; ++t) {
                bf16x4 va = *(const bf16x4*)&Vt[cur][(dt * 16 + lane16) * KSTR + t * 16 + quad * 4];
                oT[dt] = mfma_16x16x16_bf16(__builtin_bit_cast(s16x4, va), pfrag[t], oT[dt]);
            }
        __builtin_amdgcn_s_setprio(0);
    }

    // rowsum total for q = lane16: sum own partials + across the 4 quads.
    // O^T col = q = lane16 -> invt is lane-local, no broadcast needed.
    float total = (rsum[0] + rsum[1]) + (rsum[2] + rsum[3]);
    total += __shfl_xor(total, 16);
    total += __shfl_xor(total, 32);
    const float invt = 1.0f / total;

    const long orow_q = (long)(qt * 64 + w * 16 + lane16);
    #pragma unroll
    for (int dt = 0; dt < 4; ++dt) {
        const int col = h * 64 + dt * 16 + quad * 4;
        #pragma unroll
        for (int r = 0; r < 4; ++r)
            out[orow_q * (NHEAD * HDIM) + col + r] = oT[dt][r] * invt;
    }
}

extern "C" void kernel_launch(void* const* d_in, const int* in_sizes, int n_in,
                              void* d_out, int out_size, void* d_ws, size_t ws_size,
                              hipStream_t stream) {
    const float* x  = (const float*)d_in[0];
    const float* wq = (const float*)d_in[1];
    const float* wk = (const float*)d_in[2];
    const float* wv = (const float*)d_in[3];
    float* out = (float*)d_out;

    unsigned short* xbf = (unsigned short*)d_ws;                 // 2048*1024
    unsigned short* wbf = xbf + (size_t)S_LEN * HID;             // 1536*1024
    unsigned short* qkv = wbf + (size_t)NPROJ * HID;             // 2048*1280 (Q+K)
    unsigned short* vT  = qkv + (size_t)S_LEN * QKSTR;           // 256*2048  (V^T)

    cvt_all<<<dim3(3584), dim3(256), 0, stream>>>(x, wq, wk, wv, xbf, wbf);
    proj_gemm<<<dim3(16, 32), dim3(256), 0, stream>>>(xbf, wbf, qkv, vT);
    attn<<<dim3(32, 16), dim3(256), 0, stream>>>(qkv, vT, out);
}